// Round 10
// baseline (144.476 us; speedup 1.0000x reference)
//
#include <hip/hip_runtime.h>

typedef _Float16 half_t;
typedef __attribute__((ext_vector_type(8))) _Float16 half8;
typedef __attribute__((ext_vector_type(4))) _Float16 half4;
typedef __attribute__((ext_vector_type(4))) float floatx4;
typedef __attribute__((ext_vector_type(16))) float floatx16;

#define MFMA32(A, B, C) __builtin_amdgcn_mfma_f32_32x32x16_f16((A), (B), (C), 0, 0, 0)

// ----------------------------------------------------------------- k_qkv ----
// Per (t-tile tx, window w), 32x32x16 MFMA:
//   D1^T[o 0..127][t 0..127] = W[0:128] . Xw^T   (q,k — transposed form)
//   D2  [t 0..127][o 0..63]  = Xw . W[128:192]^T (v — natural form)
__global__ __launch_bounds__(256, 3) void k_qkv(
    const float* __restrict__ x, const float* __restrict__ W,
    const float* __restrict__ bias, half_t* __restrict__ q,
    half_t* __restrict__ k, half_t* __restrict__ vT,
    float* __restrict__ qp, float* __restrict__ kp) {
  __shared__ __align__(16) char smem[46080];  // Xs+Ws | E1 (overlaid)
  half_t (*Xs)[72] = (half_t (*)[72])smem;            // 18432 B [t][c]
  half_t (*Ws)[72] = (half_t (*)[72])(smem + 18432);  // 27648 B [o][c]
  half_t (*E1)[136] = (half_t (*)[136])smem;          // 34816 B [t][o], after barrier
  __shared__ float qs_l[64], ks_l[64];

  const int w = blockIdx.y, tx = blockIdx.x;
  const int t0 = tx * 128;
  const int ih = w >> 3, iw = w & 7;
  const int xbase = ih * 8192 + iw * 32;
  const int tid = threadIdx.x;

  if (tid < 64) { qs_l[tid] = 0.f; ks_l[tid] = 0.f; }

  {
    const int t = tid & 127, cg = tid >> 7;
    const int tg = t0 + t;
    const int xoff = xbase + (tg >> 5) * 256 + (tg & 31);
    half8 h8[4];
    #pragma unroll
    for (int m = 0; m < 32; m++)
      h8[m >> 3][m & 7] = (half_t)x[(cg * 32 + m) * 65536 + xoff];
    #pragma unroll
    for (int g = 0; g < 4; g++)
      *(half8*)&Xs[t][cg * 32 + g * 8] = h8[g];
  }
  for (int i = tid; i < 3072; i += 256) {
    const int o = i >> 4, c4 = (i & 15) * 4;
    const floatx4 v = *(const floatx4*)&W[o * 64 + c4];
    half4 hv;
    #pragma unroll
    for (int p = 0; p < 4; p++) hv[p] = (half_t)v[p];
    *(half4*)&Ws[o][c4] = hv;
  }
  __syncthreads();

  const int wave = tid >> 6, lane = tid & 63;
  const int ln31 = lane & 31;
  const int hk8 = (lane >> 5) * 8, hk4 = (lane >> 5) * 4;
  const int w32 = wave * 32;

  floatx16 d1[4], dv[2];
  #pragma unroll
  for (int tt = 0; tt < 4; tt++)
    #pragma unroll
    for (int r = 0; r < 16; r++) d1[tt][r] = 0.f;
  #pragma unroll
  for (int ot = 0; ot < 2; ot++)
    #pragma unroll
    for (int r = 0; r < 16; r++) dv[ot][r] = 0.f;

  #pragma unroll
  for (int kk = 0; kk < 4; kk++) {
    const int ko = kk * 16 + hk8;
    const half8 aW = *(const half8*)&Ws[w32 + ln31][ko];
    half8 bX[4];
    #pragma unroll
    for (int tt = 0; tt < 4; tt++)
      bX[tt] = *(const half8*)&Xs[tt * 32 + ln31][ko];
    const half8 bV0 = *(const half8*)&Ws[128 + ln31][ko];
    const half8 bV1 = *(const half8*)&Ws[160 + ln31][ko];
    #pragma unroll
    for (int tt = 0; tt < 4; tt++) d1[tt] = MFMA32(aW, bX[tt], d1[tt]);
    dv[0] = MFMA32(bX[wave], bV0, dv[0]);
    dv[1] = MFMA32(bX[wave], bV1, dv[1]);
  }

  {
    const int wbase = w * 65536;
    #pragma unroll
    for (int ot = 0; ot < 2; ot++) {
      const int o = ot * 32 + ln31;
      const float bv = bias[128 + o];
      #pragma unroll
      for (int g = 0; g < 4; g++) {
        const int tl = w32 + g * 8 + hk4;
        half4 pk;
        #pragma unroll
        for (int p = 0; p < 4; p++) pk[p] = (half_t)(dv[ot][g * 4 + p] + bv);
        *(half4*)&vT[wbase + o * 1024 + t0 + tl] = pk;
      }
    }
  }

  __syncthreads();

  {
    floatx4 b4[4];
    #pragma unroll
    for (int g = 0; g < 4; g++)
      b4[g] = *(const floatx4*)&bias[w32 + g * 8 + hk4];
    #pragma unroll
    for (int tt = 0; tt < 4; tt++) {
      const int t = tt * 32 + ln31;
      #pragma unroll
      for (int g = 0; g < 4; g++) {
        half4 pk;
        #pragma unroll
        for (int p = 0; p < 4; p++)
          pk[p] = (half_t)(d1[tt][g * 4 + p] + b4[g][p]);
        *(half4*)&E1[t][w32 + g * 8 + hk4] = pk;
      }
    }
  }
  __syncthreads();

  {
    const int colc = tid & 15, tgrp = tid >> 4;
    const int o8 = (colc & 7) * 8;
    half_t* __restrict__ base = (colc < 8) ? q : k;
    float sums[8];
    #pragma unroll
    for (int p = 0; p < 8; p++) sums[p] = 0.f;
    #pragma unroll
    for (int j = 0; j < 8; j++) {
      const int t = tgrp * 8 + j;
      const half8 v8 = *(const half8*)&E1[t][colc * 8];
      *(half8*)&base[w * 65536 + (t0 + t) * 64 + o8] = v8;
      #pragma unroll
      for (int p = 0; p < 8; p++) sums[p] += (float)v8[p];
    }
    float* sl = (colc < 8) ? qs_l : ks_l;
    #pragma unroll
    for (int p = 0; p < 8; p++) atomicAdd(&sl[o8 + p], sums[p]);
  }
  __syncthreads();
  if (tid < 64) {
    qp[(w * 8 + tx) * 64 + tid] = qs_l[tid];
    kp[(w * 8 + tx) * 64 + tid] = ks_l[tid];
  }
}

// ------------------------------------------------------------------ k_ar ----
__global__ __launch_bounds__(256) void k_ar(const float* __restrict__ qp,
                                            const float* __restrict__ kp,
                                            half_t* __restrict__ arH) {
  __shared__ float qs[64][65];
  __shared__ float ks[64][65];
  const int tid = threadIdx.x;
  for (int e = tid; e < 4096; e += 256) {
    const int i = e >> 6, c = e & 63;
    float sq = 0.f, sk = 0.f;
    #pragma unroll
    for (int t = 0; t < 8; t++) {
      sq += qp[i * 512 + t * 64 + c];
      sk += kp[i * 512 + t * 64 + c];
    }
    qs[i][c] = sq;
    ks[i][c] = sk;
  }
  __syncthreads();
  const float scale = 1.f / (1024.f * 1024.f);
  const int e = blockIdx.x * 256 + tid;
  const int i = e >> 6, j = e & 63;
  float s = 0.f;
  #pragma unroll
  for (int c = 0; c < 64; c++) s += qs[i][c] * ks[j][c];
  s *= scale;
  arH[e] = (half_t)(s > 0.f ? s : 0.f);
}

// ----------------------------------------------------------------- k_mix ----
__global__ __launch_bounds__(256) void k_mix(const half_t* __restrict__ q,
                                             const half_t* __restrict__ k,
                                             const half_t* __restrict__ arH,
                                             half_t* __restrict__ qm,
                                             half_t* __restrict__ km) {
  const half_t* __restrict__ src = blockIdx.y ? k : q;
  half_t* __restrict__ dst = blockIdx.y ? km : qm;
  const int tid = threadIdx.x;
  const int wave = tid >> 6, lane = tid & 63;
  const int ln31 = lane & 31;
  const int hk8 = (lane >> 5) * 8;

  half8 aA[2][4];
  #pragma unroll
  for (int mt = 0; mt < 2; mt++)
    #pragma unroll
    for (int kk = 0; kk < 4; kk++)
      aA[mt][kk] = *(const half8*)&arH[(mt * 32 + ln31) * 64 + kk * 16 + hk8];

  #pragma unroll
  for (int t32 = 0; t32 < 2; t32++) {
    const int pos = blockIdx.x * 256 + wave * 64 + t32 * 32 + ln31;
    half8 bB[4];
    #pragma unroll
    for (int kk = 0; kk < 4; kk++)
      #pragma unroll
      for (int jj = 0; jj < 8; jj++)
        bB[kk][jj] = src[(kk * 16 + hk8 + jj) * 65536 + pos];

    floatx16 c0, c1;
    #pragma unroll
    for (int r = 0; r < 16; r++) { c0[r] = 0.f; c1[r] = 0.f; }
    #pragma unroll
    for (int kk = 0; kk < 4; kk++) {
      c0 = MFMA32(aA[0][kk], bB[kk], c0);
      c1 = MFMA32(aA[1][kk], bB[kk], c1);
    }
    const int h4 = (lane >> 5) * 4;
    #pragma unroll
    for (int r = 0; r < 16; r++) {
      const int row = (r & 3) + h4 + 8 * (r >> 2);
      dst[row * 65536 + pos] = (half_t)c0[r];
      dst[(32 + row) * 65536 + pos] = (half_t)c1[r];
    }
  }
}

// ---------------------------------------------------------------- k_attn ----
// R5-exact version (best measured config). Per (t-tile of 128, window):
// O = relu(Qm Km^T) V over 8 s-chunks of 128. S^T = K.Q^T (A=K direct from
// global, B=Q resident); St[t][s] stride 138 (odd word stride 69 ->
// conflict-free, accepting unaligned-b64 splits); O^T = V^T.S -> C-layout
// rows=c, cols=t stores straight to out[c][h][w].
__global__ __launch_bounds__(256, 2) void k_attn(const half_t* __restrict__ qm,
                                                 const half_t* __restrict__ km,
                                                 const half_t* __restrict__ vT,
                                                 float* __restrict__ out) {
  __shared__ __align__(16) half_t Vs[64][136];   // [c][s-chunk]
  __shared__ __align__(16) half_t St[128][138];  // [t][s], pad 138
  const int w = blockIdx.y;
  const int t0 = blockIdx.x * 128;
  const int tid = threadIdx.x;
  const int wave = tid >> 6, lane = tid & 63;
  const int ln31 = lane & 31;
  const int hk8 = (lane >> 5) * 8, hk4 = (lane >> 5) * 4;
  const int w32 = wave * 32;
  const int wbase = w * 65536;

  // Q as B-fragments direct from global: B[n=t][k=c]
  half8 bQ[4][4];
  #pragma unroll
  for (int tt = 0; tt < 4; tt++)
    #pragma unroll
    for (int kk = 0; kk < 4; kk++)
      bQ[tt][kk] = *(const half8*)&qm[wbase + (t0 + tt * 32 + ln31) * 64 + kk * 16 + hk8];

  floatx16 oacc[2];
  #pragma unroll
  for (int ct = 0; ct < 2; ct++)
    #pragma unroll
    for (int r = 0; r < 16; r++) oacc[ct][r] = 0.f;

  for (int sc = 0; sc < 8; sc++) {
    const int s0 = sc * 128;
    __syncthreads();  // previous chunk's Vs/St reads done
    for (int idx = tid; idx < 1024; idx += 256) {
      const int c = idx >> 4, so = (idx & 15) * 8;
      *(half8*)&Vs[c][so] = *(const half8*)&vT[wbase + c * 1024 + s0 + so];
    }
    // K A-frags direct from global (each s-row consumed by exactly one wave)
    half8 aK[4];
    #pragma unroll
    for (int kk = 0; kk < 4; kk++)
      aK[kk] = *(const half8*)&km[wbase + (s0 + w32 + ln31) * 64 + kk * 16 + hk8];
    __syncthreads();  // Vs ready

    // S^T[s][t] = sum_c K[s][c] Q[t][c]; wave owns s-rows [w32, w32+32)
    floatx16 sacc[4];
    #pragma unroll
    for (int tt = 0; tt < 4; tt++)
      #pragma unroll
      for (int r = 0; r < 16; r++) sacc[tt][r] = 0.f;
    #pragma unroll
    for (int kk = 0; kk < 4; kk++)
      #pragma unroll
      for (int tt = 0; tt < 4; tt++)
        sacc[tt] = MFMA32(aK[kk], bQ[tt][kk], sacc[tt]);

    // relu -> packed half4 -> St[t][s] (stride 138 halves = 69 words, odd)
    #pragma unroll
    for (int tt = 0; tt < 4; tt++) {
      const int t = tt * 32 + ln31;
      #pragma unroll
      for (int g = 0; g < 4; g++) {
        const int s = w32 + g * 8 + hk4;
        half4 pk;
        #pragma unroll
        for (int p = 0; p < 4; p++) {
          const float v = sacc[tt][g * 4 + p];
          pk[p] = (half_t)(v > 0.f ? v : 0.f);
        }
        *(half4*)&St[t][s] = pk;
      }
    }
    __syncthreads();  // St ready

    // O^T[c][t] += sum_s V^T[c][s] S[s][t]: A=Vs rows (m=c), B=St rows (n=t)
    #pragma unroll
    for (int kk = 0; kk < 8; kk++) {
      const half8 bS = *(const half8*)&St[w32 + ln31][kk * 16 + hk8];
      #pragma unroll
      for (int ct = 0; ct < 2; ct++) {
        const half8 aV = *(const half8*)&Vs[ct * 32 + ln31][kk * 16 + hk8];
        oacc[ct] = MFMA32(aV, bS, oacc[ct]);
      }
    }
  }

  // Direct store: lane's col t = t0+w32+ln31 (fixed), rows c vary with reg.
  const int ih = w >> 3, iw = w & 7;
  const int obase = ih * 8192 + iw * 32;
  const int tb = ((t0 + w32) >> 5) * 256 + ln31;  // t0+w32 multiple of 32
  const int h4 = (lane >> 5) * 4;
  #pragma unroll
  for (int ct = 0; ct < 2; ct++) {
    #pragma unroll
    for (int r = 0; r < 16; r++) {
      const int c = ct * 32 + (r & 3) + h4 + 8 * (r >> 2);
      out[c * 65536 + obase + tb] = oacc[ct][r];
    }
  }
}

// ---------------------------------------------------------------- launch ----
extern "C" void kernel_launch(void* const* d_in, const int* in_sizes, int n_in,
                              void* d_out, int out_size, void* d_ws, size_t ws_size,
                              hipStream_t stream) {
  const float* x = (const float*)d_in[0];
  const float* W = (const float*)d_in[1];
  const float* bias = (const float*)d_in[2];
  float* out = (float*)d_out;

  half_t* q = (half_t*)d_ws;
  half_t* k = q + 4194304;
  half_t* vT = k + 4194304;
  half_t* qm = vT + 4194304;
  half_t* km = qm + 4194304;
  float* qp = (float*)(km + 4194304);  // 512*64
  float* kp = qp + 32768;
  half_t* arH = (half_t*)(kp + 32768); // 4096, 16B-aligned

  k_qkv<<<dim3(8, 64), 256, 0, stream>>>(x, W, bias, q, k, vT, qp, kp);
  k_ar<<<16, 256, 0, stream>>>(qp, kp, arH);
  k_mix<<<dim3(256, 2), 256, 0, stream>>>(q, k, arH, qm, km);
  k_attn<<<dim3(8, 64), 256, 0, stream>>>(qm, km, vT, out);
}